// Round 13
// baseline (242.061 us; speedup 1.0000x reference)
//
#include <hip/hip_runtime.h>
#include <hip/hip_bf16.h>

#define HID 768
#define ENTS 9
#define DD 64
#define NOUT 1152     // ENTS*2*DD
#define BATCH 16
#define SEQ 512
#define BIGF 1000000000000.0f
#define BIG8 125000000000.0f   // BIGF * 0.125, fixed pos-side reference max
#define NCHUNK 16

typedef __attribute__((ext_vector_type(8))) short short8;
typedef __attribute__((ext_vector_type(4))) short short4_t;
typedef __attribute__((ext_vector_type(4))) float floatx4;
typedef __attribute__((ext_vector_type(2))) float floatx2;
typedef __attribute__((ext_vector_type(4))) int intx4;
typedef unsigned short ushort_t;

static __device__ __forceinline__ ushort_t f2bf(float x) {
    unsigned int u = __float_as_uint(x);
    unsigned int r = (u + 0x7FFFu + ((u >> 16) & 1u)) >> 16;   // RNE
    return (ushort_t)r;
}

static __device__ __forceinline__ void gload16(const void* g, void* l) {
    __builtin_amdgcn_global_load_lds(
        (const __attribute__((address_space(1))) void*)g,
        (__attribute__((address_space(3))) void*)l, 16, 0, 0);
}

// ---------------- merged prep: RoPE tables + cvt W + cvt X ----------------
__global__ __launch_bounds__(256) void prep_kernel(
    const float* __restrict__ X, const float* __restrict__ W,
    float* __restrict__ sin_t, float* __restrict__ cos_t,
    ushort_t* __restrict__ Xb, ushort_t* __restrict__ Wt)
{
    const int tid = blockIdx.x * 256 + threadIdx.x;
    const int nth = gridDim.x * 256;

    for (int idx = tid; idx < SEQ * 32; idx += nth) {
        int m = idx >> 5, i = idx & 31;
        float inv = powf(10000.0f, -2.0f * (float)i / 64.0f);
        float ang = (float)m * inv;
        sin_t[idx] = sinf(ang);
        cos_t[idx] = cosf(ang);
    }
    for (int idx = tid; idx < NOUT * HID; idx += nth) {
        int n = idx / HID, k = idx - n * HID;
        Wt[idx] = f2bf(W[(size_t)k * NOUT + n]);
    }
    const int nx4 = BATCH * SEQ * HID / 4;
    for (int idx = tid; idx < nx4; idx += nth) {
        float4 f = *(const float4*)&X[idx * 4];
        ushort_t* p = &Xb[idx * 4];
        p[0] = f2bf(f.x); p[1] = f2bf(f.y); p[2] = f2bf(f.z); p[3] = f2bf(f.w);
    }
}

// ---------------- Projection GEMM + bias + RoPE + pack to q/k bf16 ----------------
__global__ __launch_bounds__(256) void proj_rope_kernel(
    const ushort_t* __restrict__ Xb, const ushort_t* __restrict__ Wt,
    const float* __restrict__ bias,
    const float* __restrict__ sin_t, const float* __restrict__ cos_t,
    ushort_t* __restrict__ qbuf, ushort_t* __restrict__ kbuf)
{
    __shared__ ushort_t As[128 * 32];   // linear: global_load_lds dest
    __shared__ ushort_t Bs[128 * 32];
    const int tid  = threadIdx.x;
    const int lane = tid & 63;
    const int wave = tid >> 6;
    const int bm = blockIdx.x * 128;
    const int bn = blockIdx.y * 128;
    const int wm = (wave >> 1) * 64;
    const int wn = (wave & 1) * 64;

    floatx4 acc[4][4];
    #pragma unroll
    for (int j = 0; j < 4; ++j)
        #pragma unroll
        for (int i = 0; i < 4; ++i) { floatx4 z = {0.f,0.f,0.f,0.f}; acc[j][i] = z; }

    const int c0 = wave * 64 + lane;
    const int c1 = 256 + wave * 64 + lane;
    const int r0 = c0 >> 2, q0 = (c0 & 3) * 8;
    const int r1 = c1 >> 2, q1 = (c1 & 3) * 8;
    ushort_t* ldsA0 = As + wave * 512;
    ushort_t* ldsA1 = As + 2048 + wave * 512;
    ushort_t* ldsB0 = Bs + wave * 512;
    ushort_t* ldsB1 = Bs + 2048 + wave * 512;

    const int ko = (lane >> 4) * 8;
    const int lr = lane & 15;

    for (int kt = 0; kt < HID; kt += 32) {
        gload16(&Xb[(size_t)(bm + r0) * HID + kt + q0], ldsA0);
        gload16(&Xb[(size_t)(bm + r1) * HID + kt + q1], ldsA1);
        gload16(&Wt[(size_t)(bn + r0) * HID + kt + q0], ldsB0);
        gload16(&Wt[(size_t)(bn + r1) * HID + kt + q1], ldsB1);
        __syncthreads();

        short8 a[4], b[4];
        #pragma unroll
        for (int i = 0; i < 4; ++i) a[i] = *(const short8*)&As[(wm + i*16 + lr) * 32 + ko];
        #pragma unroll
        for (int j = 0; j < 4; ++j) b[j] = *(const short8*)&Bs[(wn + j*16 + lr) * 32 + ko];
        #pragma unroll
        for (int j = 0; j < 4; ++j)
            #pragma unroll
            for (int i = 0; i < 4; ++i)
                acc[j][i] = __builtin_amdgcn_mfma_f32_16x16x32_bf16(b[j], a[i], acc[j][i], 0, 0, 0);
        __syncthreads();
    }

    #pragma unroll
    for (int j = 0; j < 4; ++j) {
        const int n0 = bn + wn + j*16 + (lane >> 4) * 4;   // 4 consecutive n
        const int e   = n0 >> 7;
        const int dd0 = n0 & 127;
        const bool isq = dd0 < DD;
        const int d0  = isq ? dd0 : dd0 - DD;              // multiple of 4
        const float4 bv = *(const float4*)&bias[n0];
        #pragma unroll
        for (int i = 0; i < 4; ++i) {
            const int m = bm + wm + i*16 + lr;
            const int s  = m & (SEQ - 1);
            const int bb = m >> 9;
            const float c0f = cos_t[s*32 + (d0 >> 1)];
            const float s0f = sin_t[s*32 + (d0 >> 1)];
            const float c1f = cos_t[s*32 + (d0 >> 1) + 1];
            const float s1f = sin_t[s*32 + (d0 >> 1) + 1];
            const float v0 = acc[j][i][0] + bv.x;
            const float v1 = acc[j][i][1] + bv.y;
            const float v2 = acc[j][i][2] + bv.z;
            const float v3 = acc[j][i][3] + bv.w;
            const float o0 = v0 * c0f - v1 * s0f;
            const float o1 = v1 * c0f + v0 * s0f;
            const float o2 = v2 * c1f - v3 * s1f;
            const float o3 = v3 * c1f + v2 * s1f;
            short4_t sv = { (short)f2bf(o0), (short)f2bf(o1), (short)f2bf(o2), (short)f2bf(o3) };
            size_t oidx = (((size_t)(bb * ENTS + e) * SEQ) + s) * DD + d0;
            *(short4_t*)&(isq ? qbuf : kbuf)[oidx] = sv;
        }
    }
}

// ---------------- Persistent unified QK^T / lower-fill + FUSED CE ----------------
// 768 blocks x 3 items (w = blockIdx.x*3 + t). Q/K staging for item t+1 is
// issued into registers DURING item t's compute (T14 issue-early/write-late):
// at item top, LDS write costs ~0 (loads already landed) + 2 barriers instead
// of a full global-latency drain. Reads stay in flight continuously.
#define IS_FULL(w_) ((((w_) & 15) >> 2) <= (((w_) & 15) & 3))
#define STAGE(w_) do {                                                          \
    const int bh_ = (w_) >> 4, xy_ = (w_) & 15;                                 \
    const size_t base_ = (size_t)bh_ * SEQ * DD;                                \
    const ushort_t* gq_ = &qbuf[base_ + (size_t)(((xy_ >> 2) * 128) + r) * DD + ks]; \
    const ushort_t* gk_ = &kbuf[base_ + (size_t)(((xy_ & 3) * 128) + r) * DD + ks];  \
    S[0] = *(const short8*)(gq_);      S[1] = *(const short8*)(gq_ + 8);        \
    S[2] = *(const short8*)(gq_ + 16); S[3] = *(const short8*)(gq_ + 24);       \
    S[4] = *(const short8*)(gk_);      S[5] = *(const short8*)(gk_ + 8);        \
    S[6] = *(const short8*)(gk_ + 16); S[7] = *(const short8*)(gk_ + 24);       \
} while (0)

__global__ __launch_bounds__(256, 3) void qk_mask_ce_kernel(
    const ushort_t* __restrict__ qbuf, const ushort_t* __restrict__ kbuf,
    const int* __restrict__ amask, const int* __restrict__ labels,
    float* __restrict__ logits, float* __restrict__ partials)
{
    __shared__ ushort_t Qs[128][72];
    __shared__ ushort_t Ks[128][72];
    __shared__ float ssn[4], ssp[4];
    const int tid  = threadIdx.x;
    const int lane = tid & 63;
    const int wave = tid >> 6;
    const int g  = lane >> 4;
    const int lr = lane & 15;
    const int ko = g * 8;
    const int r  = tid >> 1;            // staging row (0..127)
    const int ks = (tid & 1) * 32;      // staging col base

    short8 S[8];                        // next-item q/k staging (32 VGPR)
    const int w0 = blockIdx.x * 3;
    if (IS_FULL(w0)) STAGE(w0);

    for (int t = 0; t < 3; ++t) {
        const int w  = w0 + t;
        const int bh = w >> 4;
        const int xy = w & 15;
        const int bx = xy >> 2, by = xy & 3;
        const int bm = bx * 128, bn = by * 128;
        const int b  = bh / ENTS;
        const int bhbase = bh << 18;

        if (t > 0) __syncthreads();     // protect LDS + ssn reuse across items

        if (bx > by) {
            // ======== cheap path: constant fill + label popcount (no LDS) ========
            if (t < 2 && IS_FULL(w + 1)) STAGE(w + 1);   // lands under streaming below

            const int c4 = (tid & 31) << 2;
            const int rr = tid >> 5;
            const intx4 pf = *(const intx4*)&amask[(b << 9) + bn + c4];
            floatx4 cv;
            #pragma unroll
            for (int e = 0; e < 4; ++e) cv[e] = (float)pf[e] * BIG8 - 2.0f * BIG8;
            float cvm1 = 0.f;
            if (c4 > 0) {
                const int pfm1 = amask[(b << 9) + bn + c4 - 1];
                cvm1 = (float)pfm1 * BIG8 - 2.0f * BIG8;
            }
            const floatx4 sh = { cvm1, cv.x, cv.y, cv.z };
            const floatx2 h2 = { cv.y, cv.z };

            int cnt = 0;
            for (int pass = 0; pass < 16; ++pass) {
                const int m = bm + pass * 8 + rr;
                const int off = bhbase + (m << 9) + bn + c4;
                const intx4 y4 = *(const intx4*)&labels[off];
                #pragma unroll
                for (int e = 0; e < 4; ++e) cnt += (y4[e] & 1) & pf[e];
                if (c4 == 0) {
                    logits[off] = cv.x;
                    *(floatx2*)&logits[off + 1] = h2;
                } else {
                    *(floatx4*)&logits[off - 1] = sh;
                }
                if (c4 == 124) logits[off + 3] = cv.w;
            }

            #pragma unroll
            for (int o = 32; o > 0; o >>= 1) cnt += __shfl_down(cnt, o);
            if ((tid & 63) == 0) ssn[tid >> 6] = (float)cnt;
            __syncthreads();
            if (tid == 0) {
                float SP = ssn[0] + ssn[1] + ssn[2] + ssn[3];
                floatx2 res = { 0.f, SP };
                *(floatx2*)&partials[(size_t)(bh * NCHUNK + xy) * 2] = res;
            }
            continue;
        }

        // ======== full path ========
        const int wm = (wave >> 1) * 64;
        const int wn = (wave & 1) * 64;
        const int r0 = bm + wm + lr;
        const int W  = bn + wn;
        const int n00 = W + (g << 2);
        const bool diag = (bx == by);

        // LDS write from staged regs (vmcnt wait ~free: loads issued an item ago)
        #pragma unroll
        for (int u = 0; u < 4; ++u) *(short8*)&Qs[r][ks + u*8] = S[u];
        #pragma unroll
        for (int u = 0; u < 4; ++u) *(short8*)&Ks[r][ks + u*8] = S[4 + u];
        __syncthreads();

        // labels for jp=0 (j=0,1)
        intx4 yc[2][4];
        #pragma unroll
        for (int jh = 0; jh < 2; ++jh)
            #pragma unroll
            for (int i = 0; i < 4; ++i)
                yc[jh][i] = *(const intx4*)&labels[bhbase + ((r0 + i*16) << 9) + n00 + jh*16];

        // preload both K-step A-fragments (Q side)
        short8 a[2][4];
        #pragma unroll
        for (int kk = 0; kk < 2; ++kk)
            #pragma unroll
            for (int i = 0; i < 4; ++i)
                a[kk][i] = *(const short8*)&Qs[wm + i*16 + lr][kk*32 + ko];

        // issue next item's q/k staging (lands under this item's compute)
        if (t < 2 && IS_FULL(w + 1)) STAGE(w + 1);

        float smn = 0.f, smp = 0.f;
        float tl[4];
        float* __restrict__ lgb = logits + bhbase;

        #pragma unroll
        for (int jp = 0; jp < 2; ++jp) {
            const int jA = jp * 2, jB = jp * 2 + 1;

            floatx4 accA[4], accB[4];
            #pragma unroll
            for (int i = 0; i < 4; ++i) { floatx4 z = {0.f,0.f,0.f,0.f}; accA[i] = z; accB[i] = z; }
            #pragma unroll
            for (int kk = 0; kk < 2; ++kk) {
                const short8 bfA = *(const short8*)&Ks[wn + jA*16 + lr][kk*32 + ko];
                const short8 bfB = *(const short8*)&Ks[wn + jB*16 + lr][kk*32 + ko];
                #pragma unroll
                for (int i = 0; i < 4; ++i) {
                    accA[i] = __builtin_amdgcn_mfma_f32_16x16x32_bf16(bfA, a[kk][i], accA[i], 0, 0, 0);
                    accB[i] = __builtin_amdgcn_mfma_f32_16x16x32_bf16(bfB, a[kk][i], accB[i], 0, 0, 0);
                }
            }

            // pack current labels to bitmask (frees yc)
            unsigned int yb = 0;
            {
                int cnt = 0;
                #pragma unroll
                for (int jh = 0; jh < 2; ++jh)
                    #pragma unroll
                    for (int i = 0; i < 4; ++i)
                        #pragma unroll
                        for (int rg = 0; rg < 4; ++rg) {
                            yb |= (unsigned)(yc[jh][i][rg] & 1) << cnt;
                            ++cnt;
                        }
            }
            if (jp == 0) {   // issue jp1 labels under CE+stores
                #pragma unroll
                for (int jh = 0; jh < 2; ++jh)
                    #pragma unroll
                    for (int i = 0; i < 4; ++i)
                        yc[jh][i] = *(const intx4*)&labels[bhbase + ((r0 + i*16) << 9) + n00 + (2 + jh)*16];
            }

            // per-jp pad constants (recomputed to save VGPR)
            const intx4 p4A = *(const intx4*)&amask[(b << 9) + n00 + jA*16];
            const intx4 p4B = *(const intx4*)&amask[(b << 9) + n00 + jB*16];

            int cnt = 0;
            #pragma unroll
            for (int half = 0; half < 2; ++half) {
                const int j = half ? jB : jA;
                const intx4 p4 = half ? p4B : p4A;
                const int n0j = W + j*16 + (g << 2);
                #pragma unroll
                for (int i = 0; i < 4; ++i) {
                    const int m = r0 + i*16;
                    const int d = m - n0j;
                    floatx4 v = half ? accB[i] : accA[i];
                    #pragma unroll
                    for (int rg = 0; rg < 4; ++rg) {
                        const float pf = (float)p4[rg];
                        float tt = fmaf(v[rg], pf * 0.125f, (pf - 1.0f) * BIG8);
                        if (diag && (d > rg)) tt -= BIG8;
                        v[rg] = tt;
                        const int yy = (int)((yb >> cnt) & 1u);
                        const float uu = __uint_as_float(__float_as_uint(tt) ^ ((unsigned)yy << 31));
                        const float cN = yy ? -BIGF : 0.0f;
                        const float cP = yy ? -BIG8 : -BIGF;
                        smn += __expf(uu + cN);
                        smp += __expf(uu + cP);
                        ++cnt;
                    }
                    if (half) accB[i] = v; else accA[i] = v;
                }
            }

            // aligned full-line stores (-1-shifted windows)
            #pragma unroll
            for (int i = 0; i < 4; ++i) {
                const floatx4 vA = accA[i], vB = accB[i];
                const int m = r0 + i*16;
                float* __restrict__ row = lgb + (m << 9);
                const float sameA  = __shfl(vA.w, (lane - 16) & 63);
                const float tailA  = __shfl(tl[i], lr + 48);
                const float sameB  = __shfl(vB.w, (lane - 16) & 63);
                const float crossB = __shfl(vA.w, lr + 48);
                const float uA0 = (g == 0) ? tailA  : sameA;
                const float uB0 = (g == 0) ? crossB : sameB;
                if (jp == 0 && g == 0) {
                    row[W] = vA.x;
                    floatx2 h2 = { vA.y, vA.z };
                    *(floatx2*)&row[W + 1] = h2;
                } else {
                    floatx4 uA = { uA0, vA.x, vA.y, vA.z };
                    *(floatx4*)&row[W + jA*16 + (g << 2) - 1] = uA;
                }
                floatx4 uB = { uB0, vB.x, vB.y, vB.z };
                *(floatx4*)&row[W + jB*16 + (g << 2) - 1] = uB;
                tl[i] = vB.w;
            }
        }

        if (g == 3) {
            #pragma unroll
            for (int i = 0; i < 4; ++i) {
                const int m = r0 + i*16;
                lgb[(m << 9) + W + 63] = tl[i];
            }
        }

        #pragma unroll
        for (int off = 32; off > 0; off >>= 1) {
            smn += __shfl_down(smn, off);
            smp += __shfl_down(smp, off);
        }
        if (lane == 0) { ssn[wave] = smn; ssp[wave] = smp; }
        __syncthreads();
        if (tid == 0) {
            float SN = ssn[0] + ssn[1] + ssn[2] + ssn[3];
            float SP = ssp[0] + ssp[1] + ssp[2] + ssp[3];
            floatx2 res = { SN, SP };
            *(floatx2*)&partials[(size_t)(bh * NCHUNK + xy) * 2] = res;
        }
    }
}

static __device__ __forceinline__ float lae0(float x) {   // logaddexp(0, x)
    return fmaxf(x, 0.f) + log1pf(__expf(-fabsf(x)));
}

__global__ __launch_bounds__(256) void ce_final_kernel(
    const float* __restrict__ partials, float* __restrict__ out)
{
    __shared__ float red[256];
    const int t = threadIdx.x;
    float val = 0.f;
    if (t < BATCH * ENTS) {
        float SN = 0.f, SP = 0.f;
        for (int c = 0; c < NCHUNK; ++c) {
            SN += partials[(size_t)(t * NCHUNK + c) * 2];
            SP += partials[(size_t)(t * NCHUNK + c) * 2 + 1];
        }
        const float neg = log1pf(SN);                 // logaddexp(0, log(SN))
        const float pos = lae0(BIG8 + logf(SP));      // M_p + log(SP); SP=0 -> 0
        val = neg + pos;
    }
    red[t] = val;
    __syncthreads();
    for (int s2 = 128; s2 > 0; s2 >>= 1) {
        if (t < s2) red[t] += red[t + s2];
        __syncthreads();
    }
    if (t == 0) out[0] = red[0] / (float)(BATCH * ENTS);
}

extern "C" void kernel_launch(void* const* d_in, const int* in_sizes, int n_in,
                              void* d_out, int out_size, void* d_ws, size_t ws_size,
                              hipStream_t stream) {
    const float* X      = (const float*)d_in[0];   // (16,512,768)
    const int*   amask  = (const int*)d_in[1];     // (16,512)
    const int*   labels = (const int*)d_in[2];     // (16,9,512,512)
    const float* W      = (const float*)d_in[3];   // (768,1152)
    const float* bias   = (const float*)d_in[4];   // (1152,)

    float* out    = (float*)d_out;
    float* logits = out + 1;                       // temp_logits (16,9,512,512)

    float* sin_t = (float*)d_ws;                         // 16384 f32
    float* cos_t = sin_t + SEQ * 32;                     // 16384 f32
    ushort_t* Xb   = (ushort_t*)(cos_t + SEQ * 32);      // 6291456 bf16
    ushort_t* Wt   = Xb + (size_t)BATCH * SEQ * HID;     // 884736 bf16  [n][k]
    ushort_t* qbuf = Wt + (size_t)NOUT * HID;            // 16*9*512*64 bf16
    ushort_t* kbuf = qbuf + (size_t)BATCH * ENTS * SEQ * DD;
    float* partials = (float*)(kbuf + (size_t)BATCH * ENTS * SEQ * DD); // 144*16*2 f32

    prep_kernel<<<1024, 256, 0, stream>>>(X, W, sin_t, cos_t, Xb, Wt);
    proj_rope_kernel<<<dim3(64, 9), 256, 0, stream>>>(Xb, Wt, bias, sin_t, cos_t, qbuf, kbuf);
    qk_mask_ce_kernel<<<768, 256, 0, stream>>>(qbuf, kbuf, amask, labels, logits, partials);
    ce_final_kernel<<<1, 256, 0, stream>>>(partials, out);
}

// Round 14
// 130.390 us; speedup vs baseline: 1.8564x; 1.8564x over previous
//
#include <hip/hip_runtime.h>
#include <hip/hip_bf16.h>

#define HID 768
#define ENTS 9
#define DD 64
#define NOUT 1152     // ENTS*2*DD
#define BATCH 16
#define SEQ 512
#define BIGF 1000000000000.0f
#define BIG8 125000000000.0f   // BIGF * 0.125, fixed pos-side reference max
#define NCHUNK 16

typedef __attribute__((ext_vector_type(8))) short short8;
typedef __attribute__((ext_vector_type(4))) short short4_t;
typedef __attribute__((ext_vector_type(4))) float floatx4;
typedef __attribute__((ext_vector_type(2))) float floatx2;
typedef __attribute__((ext_vector_type(4))) int intx4;
typedef unsigned short ushort_t;

static __device__ __forceinline__ ushort_t f2bf(float x) {
    unsigned int u = __float_as_uint(x);
    unsigned int r = (u + 0x7FFFu + ((u >> 16) & 1u)) >> 16;   // RNE
    return (ushort_t)r;
}

static __device__ __forceinline__ void gload16(const void* g, void* l) {
    __builtin_amdgcn_global_load_lds(
        (const __attribute__((address_space(1))) void*)g,
        (__attribute__((address_space(3))) void*)l, 16, 0, 0);
}

// ---------------- merged prep: RoPE tables + cvt W + cvt X ----------------
__global__ __launch_bounds__(256) void prep_kernel(
    const float* __restrict__ X, const float* __restrict__ W,
    float* __restrict__ sin_t, float* __restrict__ cos_t,
    ushort_t* __restrict__ Xb, ushort_t* __restrict__ Wt)
{
    const int tid = blockIdx.x * 256 + threadIdx.x;
    const int nth = gridDim.x * 256;

    for (int idx = tid; idx < SEQ * 32; idx += nth) {
        int m = idx >> 5, i = idx & 31;
        float inv = powf(10000.0f, -2.0f * (float)i / 64.0f);
        float ang = (float)m * inv;
        sin_t[idx] = sinf(ang);
        cos_t[idx] = cosf(ang);
    }
    for (int idx = tid; idx < NOUT * HID; idx += nth) {
        int n = idx / HID, k = idx - n * HID;
        Wt[idx] = f2bf(W[(size_t)k * NOUT + n]);
    }
    const int nx4 = BATCH * SEQ * HID / 4;
    for (int idx = tid; idx < nx4; idx += nth) {
        float4 f = *(const float4*)&X[idx * 4];
        ushort_t* p = &Xb[idx * 4];
        p[0] = f2bf(f.x); p[1] = f2bf(f.y); p[2] = f2bf(f.z); p[3] = f2bf(f.w);
    }
}

// ---------------- Projection GEMM + bias + RoPE + pack to q/k bf16 ----------------
// 64(M) x 128(N) tiles -> 1152 blocks (4.5/CU avg) for better latency hiding.
// 4 waves; wave w owns all 64 rows x cols [wn=w*32, +32).
// Swapped MFMA: D[n][m]: n = bn + wn + j*16 + g*4 + rg, m = bm + i*16 + lr.
__global__ __launch_bounds__(256) void proj_rope_kernel(
    const ushort_t* __restrict__ Xb, const ushort_t* __restrict__ Wt,
    const float* __restrict__ bias,
    const float* __restrict__ sin_t, const float* __restrict__ cos_t,
    ushort_t* __restrict__ qbuf, ushort_t* __restrict__ kbuf)
{
    __shared__ ushort_t As[64 * 32];    // 4KB, linear gload16 dest
    __shared__ ushort_t Bs[128 * 32];   // 8KB
    const int tid  = threadIdx.x;
    const int lane = tid & 63;
    const int wave = tid >> 6;
    const int bm = blockIdx.x * 64;
    const int bn = blockIdx.y * 128;
    const int wn = wave * 32;

    floatx4 acc[2][4];
    #pragma unroll
    for (int j = 0; j < 2; ++j)
        #pragma unroll
        for (int i = 0; i < 4; ++i) { floatx4 z = {0.f,0.f,0.f,0.f}; acc[j][i] = z; }

    // A: 256 chunks (c = tid), B: 512 chunks (c = u*256 + tid)
    const int rA = tid >> 2, qA = (tid & 3) * 8;
    const int rB1 = 64 + (tid >> 2);
    ushort_t* ldsA  = As + wave * 512;
    ushort_t* ldsB0 = Bs + wave * 512;
    ushort_t* ldsB1 = Bs + 2048 + wave * 512;

    const int g  = lane >> 4;
    const int lr = lane & 15;
    const int ko = g * 8;

    for (int kt = 0; kt < HID; kt += 32) {
        gload16(&Xb[(size_t)(bm + rA) * HID + kt + qA], ldsA);
        gload16(&Wt[(size_t)(bn + rA) * HID + kt + qA], ldsB0);
        gload16(&Wt[(size_t)(bn + rB1) * HID + kt + qA], ldsB1);
        __syncthreads();

        short8 a[4], b[2];
        #pragma unroll
        for (int i = 0; i < 4; ++i) a[i] = *(const short8*)&As[(i*16 + lr) * 32 + ko];
        #pragma unroll
        for (int j = 0; j < 2; ++j) b[j] = *(const short8*)&Bs[(wn + j*16 + lr) * 32 + ko];
        #pragma unroll
        for (int j = 0; j < 2; ++j)
            #pragma unroll
            for (int i = 0; i < 4; ++i)
                acc[j][i] = __builtin_amdgcn_mfma_f32_16x16x32_bf16(b[j], a[i], acc[j][i], 0, 0, 0);
        __syncthreads();
    }

    const int e = blockIdx.y;           // n0>>7 is block-uniform
    #pragma unroll
    for (int j = 0; j < 2; ++j) {
        const int n0  = bn + wn + j*16 + (g << 2);   // 4 consecutive n
        const int dd0 = n0 & 127;
        const bool isq = dd0 < DD;
        const int d0  = isq ? dd0 : dd0 - DD;        // multiple of 4
        const float4 bv = *(const float4*)&bias[n0];
        #pragma unroll
        for (int i = 0; i < 4; ++i) {
            const int m = bm + i*16 + lr;
            const int s  = m & (SEQ - 1);
            const int bb = m >> 9;
            const float c0f = cos_t[s*32 + (d0 >> 1)];
            const float s0f = sin_t[s*32 + (d0 >> 1)];
            const float c1f = cos_t[s*32 + (d0 >> 1) + 1];
            const float s1f = sin_t[s*32 + (d0 >> 1) + 1];
            const float v0 = acc[j][i][0] + bv.x;
            const float v1 = acc[j][i][1] + bv.y;
            const float v2 = acc[j][i][2] + bv.z;
            const float v3 = acc[j][i][3] + bv.w;
            const float o0 = v0 * c0f - v1 * s0f;
            const float o1 = v1 * c0f + v0 * s0f;
            const float o2 = v2 * c1f - v3 * s1f;
            const float o3 = v3 * c1f + v2 * s1f;
            short4_t sv = { (short)f2bf(o0), (short)f2bf(o1), (short)f2bf(o2), (short)f2bf(o3) };
            size_t oidx = (((size_t)(bb * ENTS + e) * SEQ) + s) * DD + d0;
            *(short4_t*)&(isq ? qbuf : kbuf)[oidx] = sv;
        }
    }
}

// ---------------- Unified QK^T / lower-fill + masks -> temp_logits, FUSED CE ----------------
// (R12 kernel, unchanged — best measured state)
__global__ __launch_bounds__(256) void qk_mask_ce_kernel(
    const ushort_t* __restrict__ qbuf, const ushort_t* __restrict__ kbuf,
    const int* __restrict__ amask, const int* __restrict__ labels,
    float* __restrict__ logits, float* __restrict__ partials)
{
    __shared__ ushort_t Qs[128][72];
    __shared__ ushort_t Ks[128][72];
    __shared__ float ssn[4], ssp[4];
    const int tid  = threadIdx.x;

    // XCD-bijective swizzle (2304 % 8 == 0)
    const int wrk = (blockIdx.x & 7) * 288 + (blockIdx.x >> 3);
    const int bh = wrk >> 4;             // b*ENTS + h
    const int xy = wrk & 15;             // bx*4+by
    const int bx = xy >> 2, by = xy & 3;
    const int bm = bx * 128;
    const int bn = by * 128;
    const int b  = bh / ENTS;
    const int bhbase = bh << 18;         // bh*512*512 (fits int)

    if (bx > by) {
        // ======== cheap path: constant fill + label popcount ========
        const int c4 = (tid & 31) << 2;      // col offset in tile (0,4,...,124)
        const int rr = tid >> 5;             // 0..7

        const intx4 pf = *(const intx4*)&amask[(b << 9) + bn + c4];
        floatx4 cv;
        #pragma unroll
        for (int e = 0; e < 4; ++e) cv[e] = (float)pf[e] * BIG8 - 2.0f * BIG8;   // -(2-pf)*BIG8
        float cvm1 = 0.f;
        if (c4 > 0) {
            const int pfm1 = amask[(b << 9) + bn + c4 - 1];
            cvm1 = (float)pfm1 * BIG8 - 2.0f * BIG8;
        }
        const floatx4 sh = { cvm1, cv.x, cv.y, cv.z };
        const floatx2 h2 = { cv.y, cv.z };

        int cnt = 0;
        for (int pass = 0; pass < 16; ++pass) {
            const int m = bm + pass * 8 + rr;
            const int off = bhbase + (m << 9) + bn + c4;
            const intx4 y4 = *(const intx4*)&labels[off];
            #pragma unroll
            for (int e = 0; e < 4; ++e) cnt += (y4[e] & 1) & pf[e];
            if (c4 == 0) {
                logits[off] = cv.x;
                *(floatx2*)&logits[off + 1] = h2;
            } else {
                *(floatx4*)&logits[off - 1] = sh;
            }
            if (c4 == 124) logits[off + 3] = cv.w;   // tile tail col
        }

        #pragma unroll
        for (int o = 32; o > 0; o >>= 1) cnt += __shfl_down(cnt, o);
        if ((tid & 63) == 0) ssn[tid >> 6] = (float)cnt;
        __syncthreads();
        if (tid == 0) {
            float SP = ssn[0] + ssn[1] + ssn[2] + ssn[3];
            floatx2 res = { 0.f, SP };
            *(floatx2*)&partials[(size_t)(bh * NCHUNK + xy) * 2] = res;
        }
        return;
    }

    // ======== full path: MFMA + mask + CE ========
    const int lane = tid & 63;
    const int wave = tid >> 6;
    const int wm = (wave >> 1) * 64;
    const int wn = (wave & 1) * 64;
    const size_t base = (size_t)bh * SEQ * DD;

    const int g  = lane >> 4;
    const int lr = lane & 15;
    const int ko = g * 8;
    const int r0 = bm + wm + lr;                 // m base (i=0)
    const int W  = bn + wn;                      // wave n-column base (64-wide)
    const int n00 = W + (g << 2);

    const bool diag = (bx == by);

    // ---- labels for jp=0 only (j=0,1); jp=1 issued mid-kernel ----
    intx4 yc[2][4];
    #pragma unroll
    for (int jh = 0; jh < 2; ++jh)
        #pragma unroll
        for (int i = 0; i < 4; ++i)
            yc[jh][i] = *(const intx4*)&labels[bhbase + ((r0 + i*16) << 9) + n00 + jh*16];

    // per-j per-rg constants: pm8 = pad*0.125, pc = (pad-1)*BIG8
    floatx4 pm8[4], pc[4];
    #pragma unroll
    for (int j = 0; j < 4; ++j) {
        const intx4 p4 = *(const intx4*)&amask[(b << 9) + n00 + j*16];
        #pragma unroll
        for (int rg = 0; rg < 4; ++rg) {
            const float pf = (float)p4[rg];
            pm8[j][rg] = pf * 0.125f;
            pc[j][rg]  = (pf - 1.0f) * BIG8;
        }
    }

    // ---- stage q/k tiles to LDS ----
    {
        const int r  = tid >> 1;
        const int ks = (tid & 1) * 32;
        const ushort_t* gq = &qbuf[base + (size_t)(bm + r) * DD + ks];
        const ushort_t* gk = &kbuf[base + (size_t)(bn + r) * DD + ks];
        #pragma unroll
        for (int uu = 0; uu < 4; ++uu) {
            *(short8*)&Qs[r][ks + uu*8] = *(const short8*)(gq + uu*8);
            *(short8*)&Ks[r][ks + uu*8] = *(const short8*)(gk + uu*8);
        }
    }
    __syncthreads();

    // preload both K-step A-fragments (Q side)
    short8 a[2][4];
    #pragma unroll
    for (int kk = 0; kk < 2; ++kk)
        #pragma unroll
        for (int i = 0; i < 4; ++i)
            a[kk][i] = *(const short8*)&Qs[wm + i*16 + lr][kk*32 + ko];

    float smn = 0.f, smp = 0.f;
    float tl[4];                                  // per-row tail (valid on g==3 lanes)
    float* __restrict__ lgb = logits + bhbase;

    #pragma unroll
    for (int jp = 0; jp < 2; ++jp) {
        const int jA = jp * 2, jB = jp * 2 + 1;

        // --- MFMA for the pair ---
        floatx4 accA[4], accB[4];
        #pragma unroll
        for (int i = 0; i < 4; ++i) { floatx4 z = {0.f,0.f,0.f,0.f}; accA[i] = z; accB[i] = z; }
        #pragma unroll
        for (int kk = 0; kk < 2; ++kk) {
            const short8 bfA = *(const short8*)&Ks[wn + jA*16 + lr][kk*32 + ko];
            const short8 bfB = *(const short8*)&Ks[wn + jB*16 + lr][kk*32 + ko];
            #pragma unroll
            for (int i = 0; i < 4; ++i) {
                accA[i] = __builtin_amdgcn_mfma_f32_16x16x32_bf16(bfA, a[kk][i], accA[i], 0, 0, 0);
                accB[i] = __builtin_amdgcn_mfma_f32_16x16x32_bf16(bfB, a[kk][i], accB[i], 0, 0, 0);
            }
        }

        // --- pack current labels to a 32-bit mask; frees yc regs ---
        unsigned int yb = 0;
        {
            int cnt = 0;
            #pragma unroll
            for (int jh = 0; jh < 2; ++jh)
                #pragma unroll
                for (int i = 0; i < 4; ++i)
                    #pragma unroll
                    for (int rg = 0; rg < 4; ++rg) {
                        yb |= (unsigned)(yc[jh][i][rg] & 1) << cnt;
                        ++cnt;
                    }
        }

        // --- issue next pair's label loads (covered by CE+stores below) ---
        if (jp == 0) {
            #pragma unroll
            for (int jh = 0; jh < 2; ++jh)
                #pragma unroll
                for (int i = 0; i < 4; ++i)
                    yc[jh][i] = *(const intx4*)&labels[bhbase + ((r0 + i*16) << 9) + n00 + (2 + jh)*16];
        }

        // --- single pass: mask + scale + CE sums (cancellation-free) ---
        int cnt = 0;
        #pragma unroll
        for (int half = 0; half < 2; ++half) {
            const int j = half ? jB : jA;
            const floatx4 pm = pm8[j], pcj = pc[j];
            const int n0j = W + j*16 + (g << 2);
            #pragma unroll
            for (int i = 0; i < 4; ++i) {
                const int m = r0 + i*16;
                const int d = m - n0j;                     // m>n0j+rg <=> d>rg
                floatx4 v = half ? accB[i] : accA[i];
                #pragma unroll
                for (int rg = 0; rg < 4; ++rg) {
                    float t = fmaf(v[rg], pm[rg], pcj[rg]);
                    if (diag && (d > rg)) t -= BIG8;       // tril on diagonal blocks
                    v[rg] = t;
                    const int yy = (int)((yb >> cnt) & 1u);
                    const float uu = __uint_as_float(__float_as_uint(t) ^ ((unsigned)yy << 31));
                    const float cN = yy ? -BIGF : 0.0f;
                    const float cP = yy ? -BIG8 : -BIGF;
                    smn += __expf(uu + cN);
                    smp += __expf(uu + cP);
                    ++cnt;
                }
                if (half) accB[i] = v; else accA[i] = v;
            }
        }

        // --- aligned full-line stores (-1-shifted windows) ---
        #pragma unroll
        for (int i = 0; i < 4; ++i) {
            const floatx4 vA = accA[i], vB = accB[i];
            const int m = r0 + i*16;
            float* __restrict__ row = lgb + (m << 9);
            const float sameA  = __shfl(vA.w, (lane - 16) & 63);   // g-1's vA.w (g>0)
            const float tailA  = __shfl(tl[i], lr + 48);           // prev pair g3 tail
            const float sameB  = __shfl(vB.w, (lane - 16) & 63);   // g-1's vB.w (g>0)
            const float crossB = __shfl(vA.w, lr + 48);            // jA's g3 tail
            const float uA0 = (g == 0) ? tailA  : sameA;
            const float uB0 = (g == 0) ? crossB : sameB;
            if (jp == 0 && g == 0) {
                row[W] = vA.x;                                     // n=W       (4B, aligned)
                floatx2 h2 = { vA.y, vA.z };
                *(floatx2*)&row[W + 1] = h2;                       // n=W+1,2   (8B, aligned)
            } else {
                floatx4 uA = { uA0, vA.x, vA.y, vA.z };
                *(floatx4*)&row[W + jA*16 + (g << 2) - 1] = uA;    // 16B, aligned
            }
            floatx4 uB = { uB0, vB.x, vB.y, vB.z };
            *(floatx4*)&row[W + jB*16 + (g << 2) - 1] = uB;        // 16B, aligned
            tl[i] = vB.w;
        }
    }

    // final per-row tail stores: n = W+63 (4B, aligned), g==3 lanes hold it
    if (g == 3) {
        #pragma unroll
        for (int i = 0; i < 4; ++i) {
            const int m = r0 + i*16;
            lgb[(m << 9) + W + 63] = tl[i];
        }
    }

    // ---- wave reduce: plain sums ----
    #pragma unroll
    for (int off = 32; off > 0; off >>= 1) {
        smn += __shfl_down(smn, off);
        smp += __shfl_down(smp, off);
    }
    if (lane == 0) { ssn[wave] = smn; ssp[wave] = smp; }
    __syncthreads();
    if (tid == 0) {
        float SN = ssn[0] + ssn[1] + ssn[2] + ssn[3];
        float SP = ssp[0] + ssp[1] + ssp[2] + ssp[3];
        floatx2 res = { SN, SP };
        *(floatx2*)&partials[(size_t)(bh * NCHUNK + xy) * 2] = res;
    }
}

static __device__ __forceinline__ float lae0(float x) {   // logaddexp(0, x)
    return fmaxf(x, 0.f) + log1pf(__expf(-fabsf(x)));
}

__global__ __launch_bounds__(256) void ce_final_kernel(
    const float* __restrict__ partials, float* __restrict__ out)
{
    __shared__ float red[256];
    const int t = threadIdx.x;
    float val = 0.f;
    if (t < BATCH * ENTS) {
        float SN = 0.f, SP = 0.f;
        for (int c = 0; c < NCHUNK; ++c) {
            SN += partials[(size_t)(t * NCHUNK + c) * 2];
            SP += partials[(size_t)(t * NCHUNK + c) * 2 + 1];
        }
        const float neg = log1pf(SN);                 // logaddexp(0, log(SN))
        const float pos = lae0(BIG8 + logf(SP));      // M_p + log(SP); SP=0 -> 0
        val = neg + pos;
    }
    red[t] = val;
    __syncthreads();
    for (int s2 = 128; s2 > 0; s2 >>= 1) {
        if (t < s2) red[t] += red[t + s2];
        __syncthreads();
    }
    if (t == 0) out[0] = red[0] / (float)(BATCH * ENTS);
}

extern "C" void kernel_launch(void* const* d_in, const int* in_sizes, int n_in,
                              void* d_out, int out_size, void* d_ws, size_t ws_size,
                              hipStream_t stream) {
    const float* X      = (const float*)d_in[0];   // (16,512,768)
    const int*   amask  = (const int*)d_in[1];     // (16,512)
    const int*   labels = (const int*)d_in[2];     // (16,9,512,512)
    const float* W      = (const float*)d_in[3];   // (768,1152)
    const float* bias   = (const float*)d_in[4];   // (1152,)

    float* out    = (float*)d_out;
    float* logits = out + 1;                       // temp_logits (16,9,512,512)

    float* sin_t = (float*)d_ws;                         // 16384 f32
    float* cos_t = sin_t + SEQ * 32;                     // 16384 f32
    ushort_t* Xb   = (ushort_t*)(cos_t + SEQ * 32);      // 6291456 bf16
    ushort_t* Wt   = Xb + (size_t)BATCH * SEQ * HID;     // 884736 bf16  [n][k]
    ushort_t* qbuf = Wt + (size_t)NOUT * HID;            // 16*9*512*64 bf16
    ushort_t* kbuf = qbuf + (size_t)BATCH * ENTS * SEQ * DD;
    float* partials = (float*)(kbuf + (size_t)BATCH * ENTS * SEQ * DD); // 144*16*2 f32

    prep_kernel<<<1024, 256, 0, stream>>>(X, W, sin_t, cos_t, Xb, Wt);
    proj_rope_kernel<<<dim3(128, 9), 256, 0, stream>>>(Xb, Wt, bias, sin_t, cos_t, qbuf, kbuf);
    qk_mask_ce_kernel<<<2304, 256, 0, stream>>>(qbuf, kbuf, amask, labels, logits, partials);
    ce_final_kernel<<<1, 256, 0, stream>>>(partials, out);
}

// Round 15
// 129.663 us; speedup vs baseline: 1.8668x; 1.0056x over previous
//
#include <hip/hip_runtime.h>
#include <hip/hip_bf16.h>

#define HID 768
#define ENTS 9
#define DD 64
#define NOUT 1152     // ENTS*2*DD
#define BATCH 16
#define SEQ 512
#define BIGF 1000000000000.0f
#define BIG8 125000000000.0f   // BIGF * 0.125, fixed pos-side reference max
#define NCHUNK 16

typedef __attribute__((ext_vector_type(8))) short short8;
typedef __attribute__((ext_vector_type(4))) short short4_t;
typedef __attribute__((ext_vector_type(4))) float floatx4;
typedef __attribute__((ext_vector_type(2))) float floatx2;
typedef __attribute__((ext_vector_type(4))) int intx4;
typedef unsigned short ushort_t;

static __device__ __forceinline__ ushort_t f2bf(float x) {
    unsigned int u = __float_as_uint(x);
    unsigned int r = (u + 0x7FFFu + ((u >> 16) & 1u)) >> 16;   // RNE
    return (ushort_t)r;
}

static __device__ __forceinline__ void gload16(const void* g, void* l) {
    __builtin_amdgcn_global_load_lds(
        (const __attribute__((address_space(1))) void*)g,
        (__attribute__((address_space(3))) void*)l, 16, 0, 0);
}

// ---------------- merged prep: RoPE tables + cvt W + cvt X ----------------
__global__ __launch_bounds__(256) void prep_kernel(
    const float* __restrict__ X, const float* __restrict__ W,
    float* __restrict__ sin_t, float* __restrict__ cos_t,
    ushort_t* __restrict__ Xb, ushort_t* __restrict__ Wt)
{
    const int tid = blockIdx.x * 256 + threadIdx.x;
    const int nth = gridDim.x * 256;

    for (int idx = tid; idx < SEQ * 32; idx += nth) {
        int m = idx >> 5, i = idx & 31;
        float inv = powf(10000.0f, -2.0f * (float)i / 64.0f);
        float ang = (float)m * inv;
        sin_t[idx] = sinf(ang);
        cos_t[idx] = cosf(ang);
    }
    for (int idx = tid; idx < NOUT * HID; idx += nth) {
        int n = idx / HID, k = idx - n * HID;
        Wt[idx] = f2bf(W[(size_t)k * NOUT + n]);
    }
    const int nx4 = BATCH * SEQ * HID / 4;
    for (int idx = tid; idx < nx4; idx += nth) {
        float4 f = *(const float4*)&X[idx * 4];
        ushort_t* p = &Xb[idx * 4];
        p[0] = f2bf(f.x); p[1] = f2bf(f.y); p[2] = f2bf(f.z); p[3] = f2bf(f.w);
    }
}

// ---------------- Projection GEMM + bias + RoPE + pack to q/k bf16 ----------------
// 64(M) x 128(N) tiles -> 1152 blocks (R14 config, kept).
__global__ __launch_bounds__(256) void proj_rope_kernel(
    const ushort_t* __restrict__ Xb, const ushort_t* __restrict__ Wt,
    const float* __restrict__ bias,
    const float* __restrict__ sin_t, const float* __restrict__ cos_t,
    ushort_t* __restrict__ qbuf, ushort_t* __restrict__ kbuf)
{
    __shared__ ushort_t As[64 * 32];    // 4KB, linear gload16 dest
    __shared__ ushort_t Bs[128 * 32];   // 8KB
    const int tid  = threadIdx.x;
    const int lane = tid & 63;
    const int wave = tid >> 6;
    const int bm = blockIdx.x * 64;
    const int bn = blockIdx.y * 128;
    const int wn = wave * 32;

    floatx4 acc[2][4];
    #pragma unroll
    for (int j = 0; j < 2; ++j)
        #pragma unroll
        for (int i = 0; i < 4; ++i) { floatx4 z = {0.f,0.f,0.f,0.f}; acc[j][i] = z; }

    const int rA = tid >> 2, qA = (tid & 3) * 8;
    const int rB1 = 64 + (tid >> 2);
    ushort_t* ldsA  = As + wave * 512;
    ushort_t* ldsB0 = Bs + wave * 512;
    ushort_t* ldsB1 = Bs + 2048 + wave * 512;

    const int g  = lane >> 4;
    const int lr = lane & 15;
    const int ko = g * 8;

    for (int kt = 0; kt < HID; kt += 32) {
        gload16(&Xb[(size_t)(bm + rA) * HID + kt + qA], ldsA);
        gload16(&Wt[(size_t)(bn + rA) * HID + kt + qA], ldsB0);
        gload16(&Wt[(size_t)(bn + rB1) * HID + kt + qA], ldsB1);
        __syncthreads();

        short8 a[4], b[2];
        #pragma unroll
        for (int i = 0; i < 4; ++i) a[i] = *(const short8*)&As[(i*16 + lr) * 32 + ko];
        #pragma unroll
        for (int j = 0; j < 2; ++j) b[j] = *(const short8*)&Bs[(wn + j*16 + lr) * 32 + ko];
        #pragma unroll
        for (int j = 0; j < 2; ++j)
            #pragma unroll
            for (int i = 0; i < 4; ++i)
                acc[j][i] = __builtin_amdgcn_mfma_f32_16x16x32_bf16(b[j], a[i], acc[j][i], 0, 0, 0);
        __syncthreads();
    }

    const int e = blockIdx.y;           // n0>>7 is block-uniform
    #pragma unroll
    for (int j = 0; j < 2; ++j) {
        const int n0  = bn + wn + j*16 + (g << 2);   // 4 consecutive n
        const int dd0 = n0 & 127;
        const bool isq = dd0 < DD;
        const int d0  = isq ? dd0 : dd0 - DD;        // multiple of 4
        const float4 bv = *(const float4*)&bias[n0];
        #pragma unroll
        for (int i = 0; i < 4; ++i) {
            const int m = bm + i*16 + lr;
            const int s  = m & (SEQ - 1);
            const int bb = m >> 9;
            const float c0f = cos_t[s*32 + (d0 >> 1)];
            const float s0f = sin_t[s*32 + (d0 >> 1)];
            const float c1f = cos_t[s*32 + (d0 >> 1) + 1];
            const float s1f = sin_t[s*32 + (d0 >> 1) + 1];
            const float v0 = acc[j][i][0] + bv.x;
            const float v1 = acc[j][i][1] + bv.y;
            const float v2 = acc[j][i][2] + bv.z;
            const float v3 = acc[j][i][3] + bv.w;
            const float o0 = v0 * c0f - v1 * s0f;
            const float o1 = v1 * c0f + v0 * s0f;
            const float o2 = v2 * c1f - v3 * s1f;
            const float o3 = v3 * c1f + v2 * s1f;
            short4_t sv = { (short)f2bf(o0), (short)f2bf(o1), (short)f2bf(o2), (short)f2bf(o3) };
            size_t oidx = (((size_t)(bb * ENTS + e) * SEQ) + s) * DD + d0;
            *(short4_t*)&(isq ? qbuf : kbuf)[oidx] = sv;
        }
    }
}

// ---------------- Unified QK^T / lower-fill + masks -> temp_logits, FUSED CE ----------------
// R12 structure; CE inner loop now uses the single-exp identity: for each value
// only one of (neg,pos) exp is nonzero in f32 (the other underflows exactly),
// so arg = u + (y ? -BIG8 : 0), e = exp(arg), routed by predicated select.
__global__ __launch_bounds__(256) void qk_mask_ce_kernel(
    const ushort_t* __restrict__ qbuf, const ushort_t* __restrict__ kbuf,
    const int* __restrict__ amask, const int* __restrict__ labels,
    float* __restrict__ logits, float* __restrict__ partials)
{
    __shared__ ushort_t Qs[128][72];
    __shared__ ushort_t Ks[128][72];
    __shared__ float ssn[4], ssp[4];
    const int tid  = threadIdx.x;

    // XCD-bijective swizzle (2304 % 8 == 0)
    const int wrk = (blockIdx.x & 7) * 288 + (blockIdx.x >> 3);
    const int bh = wrk >> 4;             // b*ENTS + h
    const int xy = wrk & 15;             // bx*4+by
    const int bx = xy >> 2, by = xy & 3;
    const int bm = bx * 128;
    const int bn = by * 128;
    const int b  = bh / ENTS;
    const int bhbase = bh << 18;         // bh*512*512 (fits int)

    if (bx > by) {
        // ======== cheap path: constant fill + label popcount ========
        const int c4 = (tid & 31) << 2;      // col offset in tile (0,4,...,124)
        const int rr = tid >> 5;             // 0..7

        const intx4 pf = *(const intx4*)&amask[(b << 9) + bn + c4];
        floatx4 cv;
        #pragma unroll
        for (int e = 0; e < 4; ++e) cv[e] = (float)pf[e] * BIG8 - 2.0f * BIG8;   // -(2-pf)*BIG8
        float cvm1 = 0.f;
        if (c4 > 0) {
            const int pfm1 = amask[(b << 9) + bn + c4 - 1];
            cvm1 = (float)pfm1 * BIG8 - 2.0f * BIG8;
        }
        const floatx4 sh = { cvm1, cv.x, cv.y, cv.z };
        const floatx2 h2 = { cv.y, cv.z };

        int cnt = 0;
        for (int pass = 0; pass < 16; ++pass) {
            const int m = bm + pass * 8 + rr;
            const int off = bhbase + (m << 9) + bn + c4;
            const intx4 y4 = *(const intx4*)&labels[off];
            #pragma unroll
            for (int e = 0; e < 4; ++e) cnt += (y4[e] & 1) & pf[e];
            if (c4 == 0) {
                logits[off] = cv.x;
                *(floatx2*)&logits[off + 1] = h2;
            } else {
                *(floatx4*)&logits[off - 1] = sh;
            }
            if (c4 == 124) logits[off + 3] = cv.w;   // tile tail col
        }

        #pragma unroll
        for (int o = 32; o > 0; o >>= 1) cnt += __shfl_down(cnt, o);
        if ((tid & 63) == 0) ssn[tid >> 6] = (float)cnt;
        __syncthreads();
        if (tid == 0) {
            float SP = ssn[0] + ssn[1] + ssn[2] + ssn[3];
            floatx2 res = { 0.f, SP };
            *(floatx2*)&partials[(size_t)(bh * NCHUNK + xy) * 2] = res;
        }
        return;
    }

    // ======== full path: MFMA + mask + CE ========
    const int lane = tid & 63;
    const int wave = tid >> 6;
    const int wm = (wave >> 1) * 64;
    const int wn = (wave & 1) * 64;
    const size_t base = (size_t)bh * SEQ * DD;

    const int g  = lane >> 4;
    const int lr = lane & 15;
    const int ko = g * 8;
    const int r0 = bm + wm + lr;                 // m base (i=0)
    const int W  = bn + wn;                      // wave n-column base (64-wide)
    const int n00 = W + (g << 2);

    const bool diag = (bx == by);

    // ---- labels for jp=0 only (j=0,1); jp=1 issued mid-kernel ----
    intx4 yc[2][4];
    #pragma unroll
    for (int jh = 0; jh < 2; ++jh)
        #pragma unroll
        for (int i = 0; i < 4; ++i)
            yc[jh][i] = *(const intx4*)&labels[bhbase + ((r0 + i*16) << 9) + n00 + jh*16];

    // per-j per-rg constants: pm8 = pad*0.125, pc = (pad-1)*BIG8
    floatx4 pm8[4], pc[4];
    #pragma unroll
    for (int j = 0; j < 4; ++j) {
        const intx4 p4 = *(const intx4*)&amask[(b << 9) + n00 + j*16];
        #pragma unroll
        for (int rg = 0; rg < 4; ++rg) {
            const float pf = (float)p4[rg];
            pm8[j][rg] = pf * 0.125f;
            pc[j][rg]  = (pf - 1.0f) * BIG8;
        }
    }

    // ---- stage q/k tiles to LDS ----
    {
        const int r  = tid >> 1;
        const int ks = (tid & 1) * 32;
        const ushort_t* gq = &qbuf[base + (size_t)(bm + r) * DD + ks];
        const ushort_t* gk = &kbuf[base + (size_t)(bn + r) * DD + ks];
        #pragma unroll
        for (int uu = 0; uu < 4; ++uu) {
            *(short8*)&Qs[r][ks + uu*8] = *(const short8*)(gq + uu*8);
            *(short8*)&Ks[r][ks + uu*8] = *(const short8*)(gk + uu*8);
        }
    }
    __syncthreads();

    // preload both K-step A-fragments (Q side)
    short8 a[2][4];
    #pragma unroll
    for (int kk = 0; kk < 2; ++kk)
        #pragma unroll
        for (int i = 0; i < 4; ++i)
            a[kk][i] = *(const short8*)&Qs[wm + i*16 + lr][kk*32 + ko];

    float smn = 0.f, smp = 0.f;
    float tl[4];                                  // per-row tail (valid on g==3 lanes)
    float* __restrict__ lgb = logits + bhbase;

    #pragma unroll
    for (int jp = 0; jp < 2; ++jp) {
        const int jA = jp * 2, jB = jp * 2 + 1;

        // --- MFMA for the pair ---
        floatx4 accA[4], accB[4];
        #pragma unroll
        for (int i = 0; i < 4; ++i) { floatx4 z = {0.f,0.f,0.f,0.f}; accA[i] = z; accB[i] = z; }
        #pragma unroll
        for (int kk = 0; kk < 2; ++kk) {
            const short8 bfA = *(const short8*)&Ks[wn + jA*16 + lr][kk*32 + ko];
            const short8 bfB = *(const short8*)&Ks[wn + jB*16 + lr][kk*32 + ko];
            #pragma unroll
            for (int i = 0; i < 4; ++i) {
                accA[i] = __builtin_amdgcn_mfma_f32_16x16x32_bf16(bfA, a[kk][i], accA[i], 0, 0, 0);
                accB[i] = __builtin_amdgcn_mfma_f32_16x16x32_bf16(bfB, a[kk][i], accB[i], 0, 0, 0);
            }
        }

        // --- pack current labels to a 32-bit mask; frees yc regs ---
        unsigned int yb = 0;
        {
            int cnt = 0;
            #pragma unroll
            for (int jh = 0; jh < 2; ++jh)
                #pragma unroll
                for (int i = 0; i < 4; ++i)
                    #pragma unroll
                    for (int rg = 0; rg < 4; ++rg) {
                        yb |= (unsigned)(yc[jh][i][rg] & 1) << cnt;
                        ++cnt;
                    }
        }

        // --- issue next pair's label loads (covered by CE+stores below) ---
        if (jp == 0) {
            #pragma unroll
            for (int jh = 0; jh < 2; ++jh)
                #pragma unroll
                for (int i = 0; i < 4; ++i)
                    yc[jh][i] = *(const intx4*)&labels[bhbase + ((r0 + i*16) << 9) + n00 + (2 + jh)*16];
        }

        // --- single pass: mask + scale + CE sums (single-exp routing) ---
        int cnt = 0;
        #pragma unroll
        for (int half = 0; half < 2; ++half) {
            const int j = half ? jB : jA;
            const floatx4 pm = pm8[j], pcj = pc[j];
            const int n0j = W + j*16 + (g << 2);
            #pragma unroll
            for (int i = 0; i < 4; ++i) {
                const int m = r0 + i*16;
                const int d = m - n0j;                     // m>n0j+rg <=> d>rg
                floatx4 v = half ? accB[i] : accA[i];
                #pragma unroll
                for (int rg = 0; rg < 4; ++rg) {
                    float t = fmaf(v[rg], pm[rg], pcj[rg]);
                    if (diag && (d > rg)) t -= BIG8;       // tril on diagonal blocks
                    v[rg] = t;
                    const int yy = (int)((yb >> cnt) & 1u);
                    // u = +-t exact via sign-bit xor; y=1 shifts by fixed ref -BIG8
                    const float uu = __uint_as_float(__float_as_uint(t) ^ ((unsigned)yy << 31));
                    const float arg = yy ? (uu - BIG8) : uu;
                    const float e = __expf(arg);
                    const float ep = yy ? e : 0.0f;        // pos-side share
                    smp += ep;
                    smn += e - ep;                         // neg-side share
                    ++cnt;
                }
                if (half) accB[i] = v; else accA[i] = v;
            }
        }

        // --- aligned full-line stores (-1-shifted windows) ---
        #pragma unroll
        for (int i = 0; i < 4; ++i) {
            const floatx4 vA = accA[i], vB = accB[i];
            const int m = r0 + i*16;
            float* __restrict__ row = lgb + (m << 9);
            const float sameA  = __shfl(vA.w, (lane - 16) & 63);   // g-1's vA.w (g>0)
            const float tailA  = __shfl(tl[i], lr + 48);           // prev pair g3 tail
            const float sameB  = __shfl(vB.w, (lane - 16) & 63);   // g-1's vB.w (g>0)
            const float crossB = __shfl(vA.w, lr + 48);            // jA's g3 tail
            const float uA0 = (g == 0) ? tailA  : sameA;
            const float uB0 = (g == 0) ? crossB : sameB;
            if (jp == 0 && g == 0) {
                row[W] = vA.x;                                     // n=W       (4B, aligned)
                floatx2 h2 = { vA.y, vA.z };
                *(floatx2*)&row[W + 1] = h2;                       // n=W+1,2   (8B, aligned)
            } else {
                floatx4 uA = { uA0, vA.x, vA.y, vA.z };
                *(floatx4*)&row[W + jA*16 + (g << 2) - 1] = uA;    // 16B, aligned
            }
            floatx4 uB = { uB0, vB.x, vB.y, vB.z };
            *(floatx4*)&row[W + jB*16 + (g << 2) - 1] = uB;        // 16B, aligned
            tl[i] = vB.w;
        }
    }

    // final per-row tail stores: n = W+63 (4B, aligned), g==3 lanes hold it
    if (g == 3) {
        #pragma unroll
        for (int i = 0; i < 4; ++i) {
            const int m = r0 + i*16;
            lgb[(m << 9) + W + 63] = tl[i];
        }
    }

    // ---- wave reduce: plain sums ----
    #pragma unroll
    for (int off = 32; off > 0; off >>= 1) {
        smn += __shfl_down(smn, off);
        smp += __shfl_down(smp, off);
    }
    if (lane == 0) { ssn[wave] = smn; ssp[wave] = smp; }
    __syncthreads();
    if (tid == 0) {
        float SN = ssn[0] + ssn[1] + ssn[2] + ssn[3];
        float SP = ssp[0] + ssp[1] + ssp[2] + ssp[3];
        floatx2 res = { SN, SP };
        *(floatx2*)&partials[(size_t)(bh * NCHUNK + xy) * 2] = res;
    }
}

static __device__ __forceinline__ float lae0(float x) {   // logaddexp(0, x)
    return fmaxf(x, 0.f) + log1pf(__expf(-fabsf(x)));
}

__global__ __launch_bounds__(256) void ce_final_kernel(
    const float* __restrict__ partials, float* __restrict__ out)
{
    __shared__ float red[256];
    const int t = threadIdx.x;
    float val = 0.f;
    if (t < BATCH * ENTS) {
        float SN = 0.f, SP = 0.f;
        for (int c = 0; c < NCHUNK; ++c) {
            SN += partials[(size_t)(t * NCHUNK + c) * 2];
            SP += partials[(size_t)(t * NCHUNK + c) * 2 + 1];
        }
        const float neg = log1pf(SN);                 // logaddexp(0, log(SN))
        const float pos = lae0(BIG8 + logf(SP));      // M_p + log(SP); SP=0 -> 0
        val = neg + pos;
    }
    red[t] = val;
    __syncthreads();
    for (int s2 = 128; s2 > 0; s2 >>= 1) {
        if (t < s2) red[t] += red[t + s2];
        __syncthreads();
    }
    if (t == 0) out[0] = red[0] / (float)(BATCH * ENTS);
}

extern "C" void kernel_launch(void* const* d_in, const int* in_sizes, int n_in,
                              void* d_out, int out_size, void* d_ws, size_t ws_size,
                              hipStream_t stream) {
    const float* X      = (const float*)d_in[0];   // (16,512,768)
    const int*   amask  = (const int*)d_in[1];     // (16,512)
    const int*   labels = (const int*)d_in[2];     // (16,9,512,512)
    const float* W      = (const float*)d_in[3];   // (768,1152)
    const float* bias   = (const float*)d_in[4];   // (1152,)

    float* out    = (float*)d_out;
    float* logits = out + 1;                       // temp_logits (16,9,512,512)

    float* sin_t = (float*)d_ws;                         // 16384 f32
    float* cos_t = sin_t + SEQ * 32;                     // 16384 f32
    ushort_t* Xb   = (ushort_t*)(cos_t + SEQ * 32);      // 6291456 bf16
    ushort_t* Wt   = Xb + (size_t)BATCH * SEQ * HID;     // 884736 bf16  [n][k]
    ushort_t* qbuf = Wt + (size_t)NOUT * HID;            // 16*9*512*64 bf16
    ushort_t* kbuf = qbuf + (size_t)BATCH * ENTS * SEQ * DD;
    float* partials = (float*)(kbuf + (size_t)BATCH * ENTS * SEQ * DD); // 144*16*2 f32

    prep_kernel<<<1024, 256, 0, stream>>>(X, W, sin_t, cos_t, Xb, Wt);
    proj_rope_kernel<<<dim3(128, 9), 256, 0, stream>>>(Xb, Wt, bias, sin_t, cos_t, qbuf, kbuf);
    qk_mask_ce_kernel<<<2304, 256, 0, stream>>>(qbuf, kbuf, amask, labels, logits, partials);
    ce_final_kernel<<<1, 256, 0, stream>>>(partials, out);
}